// Round 1
// baseline (746.792 us; speedup 1.0000x reference)
//
#include <hip/hip_runtime.h>
#include <cstdint>

// Problem constants (match reference setup_inputs)
static constexpr int NU = 12000;
static constexpr int NI = 12000;
static constexpr int L  = 5;
static constexpr int PRED_DIMS = 4;
static constexpr float LAMBDA = 0.01f;   // LAMBDA_U == LAMBDA_V

static constexpr int CGRP = NI / 4;              // 3000 float4-column groups
static constexpr int NR_SPLIT = 128;             // row-parallel split
static constexpr int MAIN_THREADS = CGRP * NR_SPLIT;   // 384000
static constexpr int MAIN_BLOCKS  = MAIN_THREADS / 256; // 1500
static constexpr int REG_BLOCKS = 64;

// ---------------------------------------------------------------------------
// Masked SSE loss over R.  Each thread owns 4 consecutive columns (j..j+3):
// the 20 V values (rows j..j+3 x 5 feats) are held in registers; the thread
// strides down rows i = r0, r0+128, ...  R is read once, coalesced float4.
// U row loads are wave-uniform -> broadcast from L1.
// ---------------------------------------------------------------------------
__global__ __launch_bounds__(256) void loss_main_kernel(
        const float* __restrict__ U, const float* __restrict__ V,
        const float* __restrict__ R, double* __restrict__ partial) {
    const int gid = blockIdx.x * 256 + threadIdx.x;
    const int c  = gid % CGRP;      // float4-column group -> scalar cols 4c..4c+3
    const int r0 = gid / CGRP;      // starting row

    // V rows 4c..4c+3 = 20 contiguous floats at V[20c], 16B-aligned.
    float vv[20];
    {
        const float4* vb = reinterpret_cast<const float4*>(V + 20 * (size_t)c);
#pragma unroll
        for (int k = 0; k < 5; ++k) {
            float4 t = vb[k];
            vv[4 * k + 0] = t.x; vv[4 * k + 1] = t.y;
            vv[4 * k + 2] = t.z; vv[4 * k + 3] = t.w;
        }
    }
    // vv[j] = V[row 4c + j/5][feat j%5]; col r dot = sum_l u_l * vv[5r+l]

    double acc = 0.0;
    const float4* Rp = reinterpret_cast<const float4*>(R) + (size_t)r0 * CGRP + c;
    const size_t rstride = (size_t)NR_SPLIT * CGRP;

    for (int i = r0; i < NU; i += NR_SPLIT) {
        const float4 rv = *Rp;
        const float* Urow = U + (size_t)i * L;
        const float u0 = Urow[0], u1 = Urow[1], u2 = Urow[2],
                    u3 = Urow[3], u4 = Urow[4];

        const float d0 = u0*vv[0]  + u1*vv[1]  + u2*vv[2]  + u3*vv[3]  + u4*vv[4];
        const float d1 = u0*vv[5]  + u1*vv[6]  + u2*vv[7]  + u3*vv[8]  + u4*vv[9];
        const float d2 = u0*vv[10] + u1*vv[11] + u2*vv[12] + u3*vv[13] + u4*vv[14];
        const float d3 = u0*vv[15] + u1*vv[16] + u2*vv[17] + u3*vv[18] + u4*vv[19];

        const float e0 = rv.x - d0;
        const float e1 = rv.y - d1;
        const float e2 = rv.z - d2;
        const float e3 = rv.w - d3;

        const float s = (rv.x != 0.0f ? e0 * e0 : 0.0f)
                      + (rv.y != 0.0f ? e1 * e1 : 0.0f)
                      + (rv.z != 0.0f ? e2 * e2 : 0.0f)
                      + (rv.w != 0.0f ? e3 * e3 : 0.0f);
        acc += (double)s;
        Rp += rstride;
    }

    // wave (64) shuffle reduce, then 4-wave LDS reduce, one write per block
#pragma unroll
    for (int off = 32; off > 0; off >>= 1) acc += __shfl_down(acc, off);
    __shared__ double sacc[4];
    const int lane = threadIdx.x & 63, w = threadIdx.x >> 6;
    if (lane == 0) sacc[w] = acc;
    __syncthreads();
    if (threadIdx.x == 0)
        partial[blockIdx.x] = sacc[0] + sacc[1] + sacc[2] + sacc[3];
}

// ---------------------------------------------------------------------------
// lambda * (sum U^2 + sum V^2) partials  (64 blocks, vectorized)
// ---------------------------------------------------------------------------
__global__ __launch_bounds__(256) void reg_kernel(
        const float* __restrict__ U, const float* __restrict__ V,
        double* __restrict__ partial_reg) {
    const int gid = blockIdx.x * 256 + threadIdx.x;
    const int n4 = (NU * L) / 4;   // 15000 float4 per matrix
    double acc = 0.0;
    const float4* Uf = reinterpret_cast<const float4*>(U);
    const float4* Vf = reinterpret_cast<const float4*>(V);
    for (int k = gid; k < n4; k += REG_BLOCKS * 256) {
        float4 a = Uf[k];
        float4 b = Vf[k];
        acc += (double)(a.x*a.x + a.y*a.y + a.z*a.z + a.w*a.w
                      + b.x*b.x + b.y*b.y + b.z*b.z + b.w*b.w);
    }
#pragma unroll
    for (int off = 32; off > 0; off >>= 1) acc += __shfl_down(acc, off);
    __shared__ double sacc[4];
    const int lane = threadIdx.x & 63, w = threadIdx.x >> 6;
    if (lane == 0) sacc[w] = acc;
    __syncthreads();
    if (threadIdx.x == 0)
        partial_reg[blockIdx.x] = sacc[0] + sacc[1] + sacc[2] + sacc[3];
}

// ---------------------------------------------------------------------------
// preds[p] = dot(U[u_idx[p], :4], V[v_idx[p], :4])   (L2-resident gathers)
// ---------------------------------------------------------------------------
__global__ __launch_bounds__(256) void pred_kernel(
        const float* __restrict__ U, const float* __restrict__ V,
        const int* __restrict__ u_idx, const int* __restrict__ v_idx,
        float* __restrict__ out, int np) {
    const int p = blockIdx.x * 256 + threadIdx.x;
    if (p >= np) return;
    const int u = u_idx[p];
    const int v = v_idx[p];
    const float* up = U + (size_t)u * L;
    const float* vp = V + (size_t)v * L;
    out[1 + p] = up[0]*vp[0] + up[1]*vp[1] + up[2]*vp[2] + up[3]*vp[3];
}

// ---------------------------------------------------------------------------
// finalize: loss = sum(partial_main) + LAMBDA * sum(partial_reg)
// ---------------------------------------------------------------------------
__global__ __launch_bounds__(256) void finalize_kernel(
        const double* __restrict__ partial_main,
        const double* __restrict__ partial_reg,
        float* __restrict__ out) {
    double acc = 0.0;
    for (int k = threadIdx.x; k < MAIN_BLOCKS; k += 256) acc += partial_main[k];
    double reg = 0.0;
    for (int k = threadIdx.x; k < REG_BLOCKS; k += 256) reg += partial_reg[k];
    acc += (double)LAMBDA * reg;
#pragma unroll
    for (int off = 32; off > 0; off >>= 1) acc += __shfl_down(acc, off);
    __shared__ double sacc[4];
    const int lane = threadIdx.x & 63, w = threadIdx.x >> 6;
    if (lane == 0) sacc[w] = acc;
    __syncthreads();
    if (threadIdx.x == 0)
        out[0] = (float)(sacc[0] + sacc[1] + sacc[2] + sacc[3]);
}

extern "C" void kernel_launch(void* const* d_in, const int* in_sizes, int n_in,
                              void* d_out, int out_size, void* d_ws, size_t ws_size,
                              hipStream_t stream) {
    const float* U = (const float*)d_in[0];
    const float* V = (const float*)d_in[1];
    const float* R = (const float*)d_in[2];
    const int* u_idx = (const int*)d_in[3];
    const int* v_idx = (const int*)d_in[4];
    float* out = (float*)d_out;
    const int np = in_sizes[3];

    double* partial_main = (double*)d_ws;               // [MAIN_BLOCKS]
    double* partial_reg  = partial_main + MAIN_BLOCKS;  // [REG_BLOCKS]

    loss_main_kernel<<<MAIN_BLOCKS, 256, 0, stream>>>(U, V, R, partial_main);
    reg_kernel<<<REG_BLOCKS, 256, 0, stream>>>(U, V, partial_reg);
    pred_kernel<<<(np + 255) / 256, 256, 0, stream>>>(U, V, u_idx, v_idx, out, np);
    finalize_kernel<<<1, 256, 0, stream>>>(partial_main, partial_reg, out);
}